// Round 8
// baseline (664.360 us; speedup 1.0000x reference)
//
#include <hip/hip_runtime.h>
#include <hip/hip_bf16.h>

#define B_ 64
#define H1_ 64
#define W1_ 32
#define Hp 70
#define Wp 35
#define C_ 128
#define NH_ 4
#define HD_ 32
#define WS_ 7
#define SS_ 3
#define NWC_ 5
#define NWIN_ 50
#define NTOK_ 49
#define SCALE_ 0.17677669529663687f

typedef __hip_bfloat16 bf16;
typedef __attribute__((ext_vector_type(8))) short sh8;     // 8 bf16 = 4 VGPR
typedef __attribute__((ext_vector_type(4))) float f32x4;   // MFMA acc

__device__ __forceinline__ short f2bs(float f) {
    bf16 h = __float2bfloat16(f);
    return *reinterpret_cast<short*>(&h);
}

// ---- prep: fp32 weights -> bf16, transposed to [N][K] for MFMA B-fragments ----
__global__ void prep_k(const float* __restrict__ qkvw, const float* __restrict__ projw,
                       const float* __restrict__ f1w, const float* __restrict__ f2w,
                       short* __restrict__ ws) {
    int tid = blockIdx.x * 256 + threadIdx.x;          // 768*256 = 196608 total
    if (tid < 49152) {
        int n = tid >> 7, k = tid & 127;               // qkv_w [128][384]
        ws[tid] = f2bs(qkvw[k*384 + n]);
    } else if (tid < 65536) {
        int t = tid - 49152; int n = t >> 7, k = t & 127;   // proj_w [128][128]
        ws[tid] = f2bs(projw[k*128 + n]);
    } else if (tid < 131072) {
        int t = tid - 65536; int n = t >> 7, k = t & 127;   // fc1_w [128][512]
        ws[tid] = f2bs(f1w[k*512 + n]);
    } else if (tid < 196608) {
        int t = tid - 131072; int n = t >> 9, k = t & 511;  // fc2_w [512][128]
        ws[tid] = f2bs(f2w[k*128 + n]);
    }
}

// ---- fused: gather+LN1 -> qkv -> attention -> proj+residual (regs) ->
//      LN2 -> fc1+GELU -> fc2 -> +residual -> scatter final output ----
// LDS map (65168 B), phase A/B:
//   [0,17408)       q_s  bf16[64][136]
//   [17408,34816)   k_s  bf16[64][136]  -> cat (phase C)
//   [34816,53248)   vt   bf16[128][72]
//   [53248,62464)   xsp bf16[32][136] (A) | p_s bf16[64][72] (B)
//   [62464,65168)   rpb_s f32[676]
// phase D overlay: h2 bf16[64][136] @0 ; hv bf16[64][264] @17408 (ends 51200)
__global__ __launch_bounds__(256) void fused_k(
    const float* __restrict__ x,
    const float* __restrict__ n1g, const float* __restrict__ n1b,
    const float* __restrict__ qkvb, const float* __restrict__ rpb,
    const float* __restrict__ projb,
    const float* __restrict__ n2g, const float* __restrict__ n2b,
    const float* __restrict__ f1b, const float* __restrict__ f2b,
    const short* __restrict__ wq, const short* __restrict__ wp,
    const short* __restrict__ w1, const short* __restrict__ w2,
    float* __restrict__ out)
{
    __shared__ char smem[65168];
    short* q_s  = (short*)smem;
    short* k_s  = (short*)(smem + 17408);
    short* cat  = (short*)(smem + 17408);
    short* vt   = (short*)(smem + 34816);
    short* xsp  = (short*)(smem + 53248);
    short* p_s  = (short*)(smem + 53248);
    float* rpb_s= (float*)(smem + 62464);
    short* h2   = (short*)smem;              // phase D
    short* hv   = (short*)(smem + 17408);    // phase D

    const int tid = threadIdx.x;
    const int lane = tid & 63, wv = tid >> 6;
    const int l15 = lane & 15, l4 = lane >> 4;
    const int bw = blockIdx.x;
    const int b = bw / NWIN_, win = bw % NWIN_;
    const int wr = win / NWC_, wc = win % NWC_;

    for (int o = tid; o < 676; o += 256) rpb_s[o] = rpb[o];

    // ================= phase A: qkv (2 passes of 32 rows) =================
    #pragma unroll
    for (int pass = 0; pass < 2; ++pass) {
        const int t0 = pass * 32;
        for (int n = wv; n < 32; n += 4) {
            int gtok = t0 + n;
            int r = gtok / WS_, cc = gtok % WS_;
            int h = (wr*WS_ + r + SS_) % Hp;
            int w = (wc*WS_ + cc + SS_) % Wp;
            int c0 = lane*2;
            float v0 = 0.f, v1 = 0.f;
            if (gtok < NTOK_ && h < H1_ && w < W1_) {
                const float* src = x + ((size_t)(b*H1_*W1_ + h*W1_ + w))*C_ + c0;
                v0 = src[0]; v1 = src[1];
            }
            float s = v0 + v1, sq = v0*v0 + v1*v1;
            #pragma unroll
            for (int off = 32; off; off >>= 1) {
                s  += __shfl_xor(s, off);
                sq += __shfl_xor(sq, off);
            }
            float mean = s * (1.f/128.f);
            float var  = sq * (1.f/128.f) - mean*mean;
            float rstd = rsqrtf(var + 1e-5f);
            xsp[n*136 + c0]   = f2bs((v0-mean)*rstd*n1g[c0]   + n1b[c0]);
            xsp[n*136 + c0+1] = f2bs((v1-mean)*rstd*n1g[c0+1] + n1b[c0+1]);
        }
        __syncthreads();

        sh8 a[2][4];
        #pragma unroll
        for (int m = 0; m < 2; ++m)
            #pragma unroll
            for (int kk = 0; kk < 4; ++kk)
                a[m][kk] = *(const sh8*)(xsp + (m*16 + l15)*136 + kk*32 + l4*8);

        // prefetched weight-frag rotation
        sh8 bq[4], bqn[4];
        {
            int n0 = (wv*6)*16 + l15;
            #pragma unroll
            for (int kk = 0; kk < 4; ++kk)
                bq[kk] = *(const sh8*)(wq + n0*C_ + kk*32 + l4*8);
        }
        for (int t = 0; t < 6; ++t) {
            int n0 = (wv*6 + t)*16 + l15;
            if (t < 5) {
                int n1 = n0 + 16;
                #pragma unroll
                for (int kk = 0; kk < 4; ++kk)
                    bqn[kk] = *(const sh8*)(wq + n1*C_ + kk*32 + l4*8);
            }
            f32x4 acc0 = {0.f,0.f,0.f,0.f}, acc1 = {0.f,0.f,0.f,0.f};
            #pragma unroll
            for (int kk = 0; kk < 4; ++kk) {
                acc0 = __builtin_amdgcn_mfma_f32_16x16x32_bf16(a[0][kk], bq[kk], acc0, 0,0,0);
                acc1 = __builtin_amdgcn_mfma_f32_16x16x32_bf16(a[1][kk], bq[kk], acc1, 0,0,0);
            }
            int mat = n0 >> 7, c = n0 & 127;
            float bias = qkvb[n0];
            float scl = (mat == 0) ? SCALE_ : 1.f;
            #pragma unroll
            for (int r = 0; r < 4; ++r) {
                int m0 = t0 + l4*4 + r;
                int m1 = m0 + 16;
                float v0c = (acc0[r] + bias) * scl;
                float v1c = (acc1[r] + bias) * scl;
                if (mat == 0)      { q_s[m0*136 + c] = f2bs(v0c); q_s[m1*136 + c] = f2bs(v1c); }
                else if (mat == 1) { k_s[m0*136 + c] = f2bs(v0c); k_s[m1*136 + c] = f2bs(v1c); }
                else               { vt[c*72 + m0]   = f2bs(v0c); vt[c*72 + m1]   = f2bs(v1c); }
            }
            #pragma unroll
            for (int kk = 0; kk < 4; ++kk) bq[kk] = bqn[kk];
        }
        __syncthreads();
    }

    // ================= phase B: attention (zero-barrier head loop) =================
    int zi_r[4], ri_r[4], ci_r[4]; bool iv[4];
    #pragma unroll
    for (int r = 0; r < 4; ++r) {
        int i = wv*16 + l4*4 + r;
        iv[r] = (i < NTOK_);
        int ri = i / WS_, ci = i % WS_;
        ri_r[r] = ri; ci_r[r] = ci;
        int hi = wr*WS_ + ri, wi = wc*WS_ + ci;
        zi_r[r] = (hi < 63 ? 0 : (hi < 67 ? 1 : 2))*3 + (wi < 28 ? 0 : (wi < 32 ? 1 : 2));
    }
    int zj_n[4], rj_n[4], cj_n[4]; bool jv[4];
    #pragma unroll
    for (int nt = 0; nt < 4; ++nt) {
        int j = nt*16 + l15;
        jv[nt] = (j < NTOK_);
        int rj = j / WS_, cj = j % WS_;
        rj_n[nt] = rj; cj_n[nt] = cj;
        int hj = wr*WS_ + rj, wj = wc*WS_ + cj;
        zj_n[nt] = (hj < 63 ? 0 : (hj < 67 ? 1 : 2))*3 + (wj < 28 ? 0 : (wj < 32 ? 1 : 2));
    }

    f32x4 o_acc[4][2] = {};
    #pragma unroll
    for (int h = 0; h < NH_; ++h) {
        sh8 aq = *(const sh8*)(q_s + (wv*16 + l15)*136 + h*HD_ + l4*8);
        f32x4 s[4];
        #pragma unroll
        for (int nt = 0; nt < 4; ++nt) {
            sh8 bk = *(const sh8*)(k_s + (nt*16 + l15)*136 + h*HD_ + l4*8);
            f32x4 z = {0.f,0.f,0.f,0.f};
            s[nt] = __builtin_amdgcn_mfma_f32_16x16x32_bf16(aq, bk, z, 0,0,0);
        }
        #pragma unroll
        for (int nt = 0; nt < 4; ++nt)
            #pragma unroll
            for (int r = 0; r < 4; ++r) {
                float sv = s[nt][r];
                if (iv[r] && jv[nt]) {
                    sv += rpb_s[((ri_r[r]-rj_n[nt]+6)*13 + (ci_r[r]-cj_n[nt]+6))*4 + h];
                    if (zi_r[r] != zj_n[nt]) sv -= 100.f;
                } else sv = -1e30f;
                s[nt][r] = sv;
            }
        #pragma unroll
        for (int r = 0; r < 4; ++r) {
            float m0 = fmaxf(fmaxf(s[0][r], s[1][r]), fmaxf(s[2][r], s[3][r]));
            #pragma unroll
            for (int off = 1; off < 16; off <<= 1) m0 = fmaxf(m0, __shfl_xor(m0, off));
            float ls = 0.f;
            #pragma unroll
            for (int nt = 0; nt < 4; ++nt) {
                float e = __expf(s[nt][r] - m0);
                s[nt][r] = e; ls += e;
            }
            #pragma unroll
            for (int off = 1; off < 16; off <<= 1) ls += __shfl_xor(ls, off);
            float inv = 1.f / ls;
            #pragma unroll
            for (int nt = 0; nt < 4; ++nt)
                p_s[(wv*16 + l4*4 + r)*72 + nt*16 + l15] = f2bs(s[nt][r] * inv);
        }
        sh8 ap0 = *(const sh8*)(p_s + (wv*16 + l15)*72 + l4*8);
        sh8 ap1 = *(const sh8*)(p_s + (wv*16 + l15)*72 + 32 + l4*8);
        #pragma unroll
        for (int nt2 = 0; nt2 < 2; ++nt2) {
            sh8 bv0 = *(const sh8*)(vt + (h*HD_ + nt2*16 + l15)*72 + l4*8);
            sh8 bv1 = *(const sh8*)(vt + (h*HD_ + nt2*16 + l15)*72 + 32 + l4*8);
            o_acc[h][nt2] = __builtin_amdgcn_mfma_f32_16x16x32_bf16(ap0, bv0, o_acc[h][nt2], 0,0,0);
            o_acc[h][nt2] = __builtin_amdgcn_mfma_f32_16x16x32_bf16(ap1, bv1, o_acc[h][nt2], 0,0,0);
        }
    }

    __syncthreads();   // k_s dead -> cat may overlay

    // ================= phase C: proj + residual (kept in registers) =================
    bool pred[4]; size_t tokb[4];
    #pragma unroll
    for (int r = 0; r < 4; ++r) {
        int m = wv*16 + l4*4 + r;
        int rr = m / WS_, cc = m % WS_;
        int hh = (wr*WS_ + rr + SS_) % Hp;
        int ww = (wc*WS_ + cc + SS_) % Wp;
        pred[r] = (m < NTOK_) && (hh < H1_) && (ww < W1_);
        tokb[r] = ((size_t)(b*H1_*W1_ + hh*W1_ + ww))*C_;
    }

    #pragma unroll
    for (int h = 0; h < NH_; ++h)
        #pragma unroll
        for (int nt2 = 0; nt2 < 2; ++nt2)
            #pragma unroll
            for (int r = 0; r < 4; ++r)
                cat[(wv*16 + l4*4 + r)*136 + h*HD_ + nt2*16 + l15] = f2bs(o_acc[h][nt2][r]);

    sh8 pa[4];
    #pragma unroll
    for (int kk = 0; kk < 4; ++kk)
        pa[kk] = *(const sh8*)(cat + (wv*16 + l15)*136 + kk*32 + l4*8);

    f32x4 resid[8];
    {
        sh8 bpw[4], bpwn[4];
        #pragma unroll
        for (int kk = 0; kk < 4; ++kk)
            bpw[kk] = *(const sh8*)(wp + l15*C_ + kk*32 + l4*8);
        for (int nt = 0; nt < 8; ++nt) {
            int ch = nt*16 + l15;
            if (nt < 7) {
                #pragma unroll
                for (int kk = 0; kk < 4; ++kk)
                    bpwn[kk] = *(const sh8*)(wp + (ch+16)*C_ + kk*32 + l4*8);
            }
            f32x4 acc = {0.f,0.f,0.f,0.f};
            #pragma unroll
            for (int kk = 0; kk < 4; ++kk)
                acc = __builtin_amdgcn_mfma_f32_16x16x32_bf16(pa[kk], bpw[kk], acc, 0,0,0);
            float pbv = projb[ch];
            #pragma unroll
            for (int r = 0; r < 4; ++r)
                resid[nt][r] = pred[r] ? (x[tokb[r] + ch] + acc[r] + pbv) : 0.f;
            #pragma unroll
            for (int kk = 0; kk < 4; ++kk) bpw[kk] = bpwn[kk];
        }
    }
    __syncthreads();   // q_s/cat/vt dead -> h2/hv overlay

    // ================= phase L: LN2 (registers + 16-lane shfl) =================
    float n2gv[8], n2bv[8];
    #pragma unroll
    for (int nt = 0; nt < 8; ++nt) {
        int ch = nt*16 + l15;
        n2gv[nt] = n2g[ch]; n2bv[nt] = n2b[ch];
    }
    #pragma unroll
    for (int r = 0; r < 4; ++r) {
        float s = 0.f, sq = 0.f;
        #pragma unroll
        for (int nt = 0; nt < 8; ++nt) {
            float v = resid[nt][r];
            s += v; sq += v*v;
        }
        #pragma unroll
        for (int off = 1; off < 16; off <<= 1) {
            s  += __shfl_xor(s, off);
            sq += __shfl_xor(sq, off);
        }
        float mean = s * (1.f/128.f);
        float var  = sq * (1.f/128.f) - mean*mean;
        float rstd = rsqrtf(var + 1e-5f);
        int m = wv*16 + l4*4 + r;
        #pragma unroll
        for (int nt = 0; nt < 8; ++nt)
            h2[m*136 + nt*16 + l15] = f2bs((resid[nt][r] - mean)*rstd*n2gv[nt] + n2bv[nt]);
    }
    __syncthreads();

    // ================= phase D: fc1 + GELU -> fc2 (two 256-hidden chunks) =================
    sh8 a1[4];
    #pragma unroll
    for (int kk = 0; kk < 4; ++kk)
        a1[kk] = *(const sh8*)(h2 + (wv*16 + l15)*136 + kk*32 + l4*8);

    f32x4 facc[8] = {};
    #pragma unroll 1
    for (int chunk = 0; chunk < 2; ++chunk) {
        const int c0 = chunk*256;
        // ---- fc1 for hidden cols c0..c0+255 ----
        {
            sh8 b1[4], b1n[4];
            #pragma unroll
            for (int kk = 0; kk < 4; ++kk)
                b1[kk] = *(const sh8*)(w1 + (c0 + l15)*C_ + kk*32 + l4*8);
            for (int t = 0; t < 16; ++t) {
                int n = c0 + t*16 + l15;
                if (t < 15) {
                    #pragma unroll
                    for (int kk = 0; kk < 4; ++kk)
                        b1n[kk] = *(const sh8*)(w1 + (n+16)*C_ + kk*32 + l4*8);
                }
                f32x4 acc = {0.f,0.f,0.f,0.f};
                #pragma unroll
                for (int kk = 0; kk < 4; ++kk)
                    acc = __builtin_amdgcn_mfma_f32_16x16x32_bf16(a1[kk], b1[kk], acc, 0,0,0);
                float bias = f1b[n];
                #pragma unroll
                for (int r = 0; r < 4; ++r) {
                    float xv = acc[r] + bias;
                    float g = xv * 0.5f * (1.f + erff(xv * 0.70710678118654752f));
                    int m = wv*16 + l4*4 + r;
                    hv[m*264 + t*16 + l15] = f2bs(g);
                }
                #pragma unroll
                for (int kk = 0; kk < 4; ++kk) b1[kk] = b1n[kk];
            }
        }
        __syncthreads();
        // ---- fc2 partial: K = c0..c0+255 (8 k-steps) ----
        {
            sh8 av, avn;
            sh8 b2[8], b2n[8];
            av = *(const sh8*)(hv + (wv*16 + l15)*264 + l4*8);
            #pragma unroll
            for (int nt = 0; nt < 8; ++nt)
                b2[nt] = *(const sh8*)(w2 + (nt*16 + l15)*512 + c0 + l4*8);
            for (int kk2 = 0; kk2 < 8; ++kk2) {
                if (kk2 < 7) {
                    avn = *(const sh8*)(hv + (wv*16 + l15)*264 + (kk2+1)*32 + l4*8);
                    #pragma unroll
                    for (int nt = 0; nt < 8; ++nt)
                        b2n[nt] = *(const sh8*)(w2 + (nt*16 + l15)*512 + c0 + (kk2+1)*32 + l4*8);
                }
                #pragma unroll
                for (int nt = 0; nt < 8; ++nt)
                    facc[nt] = __builtin_amdgcn_mfma_f32_16x16x32_bf16(av, b2[nt], facc[nt], 0,0,0);
                av = avn;
                #pragma unroll
                for (int nt = 0; nt < 8; ++nt) b2[nt] = b2n[nt];
            }
        }
        if (chunk == 0) __syncthreads();   // hv rewritten by next fc1
    }

    // ================= phase E: final residual + scatter =================
    #pragma unroll
    for (int nt = 0; nt < 8; ++nt) {
        int ch = nt*16 + l15;
        float bias = f2b[ch];
        #pragma unroll
        for (int r = 0; r < 4; ++r) {
            if (pred[r])
                out[tokb[r] + ch] = resid[nt][r] + facc[nt][r] + bias;
        }
    }
}

extern "C" void kernel_launch(void* const* d_in, const int* in_sizes, int n_in,
                              void* d_out, int out_size, void* d_ws, size_t ws_size,
                              hipStream_t stream) {
    const float* x    = (const float*)d_in[0];
    const float* n1g  = (const float*)d_in[1];
    const float* n1b  = (const float*)d_in[2];
    const float* qkvw = (const float*)d_in[3];
    const float* qkvb = (const float*)d_in[4];
    const float* rpb  = (const float*)d_in[5];
    const float* pw   = (const float*)d_in[6];
    const float* pb   = (const float*)d_in[7];
    const float* n2g  = (const float*)d_in[8];
    const float* n2b  = (const float*)d_in[9];
    const float* f1w  = (const float*)d_in[10];
    const float* f1b  = (const float*)d_in[11];
    const float* f2w  = (const float*)d_in[12];
    const float* f2b  = (const float*)d_in[13];

    short* ws = (short*)d_ws;          // bf16 transposed weights
    const short* wq = ws;
    const short* wp = ws + 49152;
    const short* w1 = ws + 65536;
    const short* w2 = ws + 131072;

    hipLaunchKernelGGL(prep_k, dim3(768), dim3(256), 0, stream, qkvw, pw, f1w, f2w, ws);
    hipLaunchKernelGGL(fused_k, dim3(B_*NWIN_), dim3(256), 0, stream,
                       x, n1g, n1b, qkvb, rpb, pb, n2g, n2b, f1b, f2b,
                       wq, wp, w1, w2, (float*)d_out);
}

// Round 9
// 449.245 us; speedup vs baseline: 1.4788x; 1.4788x over previous
//
#include <hip/hip_runtime.h>
#include <hip/hip_bf16.h>

#define B_ 64
#define H1_ 64
#define W1_ 32
#define Hp 70
#define Wp 35
#define C_ 128
#define NH_ 4
#define HD_ 32
#define WS_ 7
#define SS_ 3
#define NWC_ 5
#define NWIN_ 50
#define NTOK_ 49
#define SCALE_ 0.17677669529663687f

typedef __hip_bfloat16 bf16;
typedef __attribute__((ext_vector_type(8))) short sh8;     // 8 bf16 = 4 VGPR
typedef __attribute__((ext_vector_type(4))) float f32x4;   // MFMA acc

__device__ __forceinline__ float bs2f(short s) {
    unsigned int u = ((unsigned int)(unsigned short)s) << 16;
    float f; __builtin_memcpy(&f, &u, 4); return f;
}
__device__ __forceinline__ short f2bs(float f) {
    bf16 h = __float2bfloat16(f);
    return *reinterpret_cast<short*>(&h);
}

// ---- prep: fp32 weights -> bf16, transposed to [N][K] for MFMA B-fragments ----
__global__ void prep_k(const float* __restrict__ qkvw, const float* __restrict__ projw,
                       const float* __restrict__ f1w, const float* __restrict__ f2w,
                       short* __restrict__ ws) {
    int tid = blockIdx.x * 256 + threadIdx.x;          // 768*256 = 196608 total
    if (tid < 49152) {
        int n = tid >> 7, k = tid & 127;               // qkv_w [128][384]
        ws[tid] = f2bs(qkvw[k*384 + n]);
    } else if (tid < 65536) {
        int t = tid - 49152; int n = t >> 7, k = t & 127;   // proj_w [128][128]
        ws[tid] = f2bs(projw[k*128 + n]);
    } else if (tid < 131072) {
        int t = tid - 65536; int n = t >> 7, k = t & 127;   // fc1_w [128][512]
        ws[tid] = f2bs(f1w[k*512 + n]);
    } else if (tid < 196608) {
        int t = tid - 131072; int n = t >> 9, k = t & 511;  // fc2_w [512][128]
        ws[tid] = f2bs(f2w[k*128 + n]);
    }
}

// ---- win_attn, 8 waves: gather+LN1 -> qkv -> attention -> proj+residual scatter ----
// Wave w: mt = w&3 (16-row m-tile), hg = w>>2 (head-pair / col-half).
// LDS map (71680 B, 2 blocks/CU):
//   [0,17408)       q_s  bf16[64][136]
//   [17408,34816)   k_s  bf16[64][136]  -> cat (phase C)
//   [34816,53248)   vt   bf16[128][72]  (V transposed: [ch][tok])
//   [53248,71680)   xsp bf16[32][136] (A, 8704) | p_s bf16[8][16][72] (B, per-wave)
__global__ __launch_bounds__(512, 4) void win_attn(
    const float* __restrict__ x,
    const float* __restrict__ n1g, const float* __restrict__ n1b,
    const float* __restrict__ qkvb, const float* __restrict__ rpb,
    const float* __restrict__ projb,
    const short* __restrict__ wq, const short* __restrict__ wp,
    float* __restrict__ out)
{
    __shared__ char smem[71680];
    short* q_s = (short*)smem;
    short* k_s = (short*)(smem + 17408);
    short* cat = (short*)(smem + 17408);
    short* vt  = (short*)(smem + 34816);
    short* xsp = (short*)(smem + 53248);
    short* p_s = (short*)(smem + 53248);

    const int tid = threadIdx.x;
    const int lane = tid & 63, wv = tid >> 6;
    const int l15 = lane & 15, l4 = lane >> 4;
    const int mt = wv & 3, hg = wv >> 2;
    const int bw = blockIdx.x;
    const int b = bw / NWIN_, win = bw % NWIN_;
    const int wr = win / NWC_, wc = win % NWC_;

    // ================= phase A: qkv (2 passes of 32 rows) =================
    #pragma unroll
    for (int pass = 0; pass < 2; ++pass) {
        const int t0 = pass * 32;
        for (int n = wv; n < 32; n += 8) {
            int gtok = t0 + n;
            int r = gtok / WS_, cc = gtok % WS_;
            int h = (wr*WS_ + r + SS_) % Hp;
            int w = (wc*WS_ + cc + SS_) % Wp;
            int c0 = lane*2;
            float v0 = 0.f, v1 = 0.f;
            if (gtok < NTOK_ && h < H1_ && w < W1_) {
                const float* src = x + ((size_t)(b*H1_*W1_ + h*W1_ + w))*C_ + c0;
                v0 = src[0]; v1 = src[1];
            }
            float s = v0 + v1, sq = v0*v0 + v1*v1;
            #pragma unroll
            for (int off = 32; off; off >>= 1) {
                s  += __shfl_xor(s, off);
                sq += __shfl_xor(sq, off);
            }
            float mean = s * (1.f/128.f);
            float var  = sq * (1.f/128.f) - mean*mean;
            float rstd = rsqrtf(var + 1e-5f);
            xsp[n*136 + c0]   = f2bs((v0-mean)*rstd*n1g[c0]   + n1b[c0]);
            xsp[n*136 + c0+1] = f2bs((v1-mean)*rstd*n1g[c0+1] + n1b[c0+1]);
        }
        __syncthreads();

        sh8 a[2][4];
        #pragma unroll
        for (int m = 0; m < 2; ++m)
            #pragma unroll
            for (int kk = 0; kk < 4; ++kk)
                a[m][kk] = *(const sh8*)(xsp + (m*16 + l15)*136 + kk*32 + l4*8);

        sh8 bq[4], bqn[4];
        {
            int n0 = (wv*3)*16 + l15;
            #pragma unroll
            for (int kk = 0; kk < 4; ++kk)
                bq[kk] = *(const sh8*)(wq + n0*C_ + kk*32 + l4*8);
        }
        for (int t = 0; t < 3; ++t) {
            int n0 = (wv*3 + t)*16 + l15;
            if (t < 2) {
                int n1 = n0 + 16;
                #pragma unroll
                for (int kk = 0; kk < 4; ++kk)
                    bqn[kk] = *(const sh8*)(wq + n1*C_ + kk*32 + l4*8);
            }
            f32x4 acc0 = {0.f,0.f,0.f,0.f}, acc1 = {0.f,0.f,0.f,0.f};
            #pragma unroll
            for (int kk = 0; kk < 4; ++kk) {
                acc0 = __builtin_amdgcn_mfma_f32_16x16x32_bf16(a[0][kk], bq[kk], acc0, 0,0,0);
                acc1 = __builtin_amdgcn_mfma_f32_16x16x32_bf16(a[1][kk], bq[kk], acc1, 0,0,0);
            }
            int mat = n0 >> 7, c = n0 & 127;
            float bias = qkvb[n0];
            float scl = (mat == 0) ? SCALE_ : 1.f;
            #pragma unroll
            for (int r = 0; r < 4; ++r) {
                int m0 = t0 + l4*4 + r;
                int m1 = m0 + 16;
                float v0c = (acc0[r] + bias) * scl;
                float v1c = (acc1[r] + bias) * scl;
                if (mat == 0)      { q_s[m0*136 + c] = f2bs(v0c); q_s[m1*136 + c] = f2bs(v1c); }
                else if (mat == 1) { k_s[m0*136 + c] = f2bs(v0c); k_s[m1*136 + c] = f2bs(v1c); }
                else               { vt[c*72 + m0]   = f2bs(v0c); vt[c*72 + m1]   = f2bs(v1c); }
            }
            #pragma unroll
            for (int kk = 0; kk < 4; ++kk) bq[kk] = bqn[kk];
        }
        __syncthreads();
    }

    // ================= phase B: attention; wave = (mt, heads hg*2..hg*2+1) =================
    int zi_r[4], ri_r[4], ci_r[4]; bool iv[4];
    #pragma unroll
    for (int r = 0; r < 4; ++r) {
        int i = mt*16 + l4*4 + r;
        iv[r] = (i < NTOK_);
        int ri = i / WS_, ci = i % WS_;
        ri_r[r] = ri; ci_r[r] = ci;
        int hi = wr*WS_ + ri, wi = wc*WS_ + ci;
        zi_r[r] = (hi < 63 ? 0 : (hi < 67 ? 1 : 2))*3 + (wi < 28 ? 0 : (wi < 32 ? 1 : 2));
    }
    int zj_n[4], rj_n[4], cj_n[4]; bool jv[4];
    #pragma unroll
    for (int nt = 0; nt < 4; ++nt) {
        int j = nt*16 + l15;
        jv[nt] = (j < NTOK_);
        int rj = j / WS_, cj = j % WS_;
        rj_n[nt] = rj; cj_n[nt] = cj;
        int hj = wr*WS_ + rj, wj = wc*WS_ + cj;
        zj_n[nt] = (hj < 63 ? 0 : (hj < 67 ? 1 : 2))*3 + (wj < 28 ? 0 : (wj < 32 ? 1 : 2));
    }

    short* myp = p_s + wv*16*72;     // per-wave P slice
    f32x4 o_acc[2][2] = {};
    #pragma unroll
    for (int hl = 0; hl < 2; ++hl) {
        const int h = hg*2 + hl;
        sh8 aq = *(const sh8*)(q_s + (mt*16 + l15)*136 + h*HD_ + l4*8);
        f32x4 s[4];
        #pragma unroll
        for (int nt = 0; nt < 4; ++nt) {
            sh8 bk = *(const sh8*)(k_s + (nt*16 + l15)*136 + h*HD_ + l4*8);
            f32x4 z = {0.f,0.f,0.f,0.f};
            s[nt] = __builtin_amdgcn_mfma_f32_16x16x32_bf16(aq, bk, z, 0,0,0);
        }
        #pragma unroll
        for (int nt = 0; nt < 4; ++nt)
            #pragma unroll
            for (int r = 0; r < 4; ++r) {
                float sv = s[nt][r];
                if (iv[r] && jv[nt]) {
                    sv += rpb[(size_t)((ri_r[r]-rj_n[nt]+6)*13 + (ci_r[r]-cj_n[nt]+6))*4 + h];
                    if (zi_r[r] != zj_n[nt]) sv -= 100.f;
                } else sv = -1e30f;
                s[nt][r] = sv;
            }
        #pragma unroll
        for (int r = 0; r < 4; ++r) {
            float m0 = fmaxf(fmaxf(s[0][r], s[1][r]), fmaxf(s[2][r], s[3][r]));
            #pragma unroll
            for (int off = 1; off < 16; off <<= 1) m0 = fmaxf(m0, __shfl_xor(m0, off));
            float ls = 0.f;
            #pragma unroll
            for (int nt = 0; nt < 4; ++nt) {
                float e = __expf(s[nt][r] - m0);
                s[nt][r] = e; ls += e;
            }
            #pragma unroll
            for (int off = 1; off < 16; off <<= 1) ls += __shfl_xor(ls, off);
            float inv = 1.f / ls;
            #pragma unroll
            for (int nt = 0; nt < 4; ++nt)
                myp[(l4*4 + r)*72 + nt*16 + l15] = f2bs(s[nt][r] * inv);
        }
        sh8 ap0 = *(const sh8*)(myp + l15*72 + l4*8);
        sh8 ap1 = *(const sh8*)(myp + l15*72 + 32 + l4*8);
        #pragma unroll
        for (int nt2 = 0; nt2 < 2; ++nt2) {
            sh8 bv0 = *(const sh8*)(vt + (h*HD_ + nt2*16 + l15)*72 + l4*8);
            sh8 bv1 = *(const sh8*)(vt + (h*HD_ + nt2*16 + l15)*72 + 32 + l4*8);
            o_acc[hl][nt2] = __builtin_amdgcn_mfma_f32_16x16x32_bf16(ap0, bv0, o_acc[hl][nt2], 0,0,0);
            o_acc[hl][nt2] = __builtin_amdgcn_mfma_f32_16x16x32_bf16(ap1, bv1, o_acc[hl][nt2], 0,0,0);
        }
    }

    __syncthreads();   // k_s reads done -> cat may overlay

    // ================= phase C: cat -> proj -> +residual scatter =================
    #pragma unroll
    for (int hl = 0; hl < 2; ++hl)
        #pragma unroll
        for (int nt2 = 0; nt2 < 2; ++nt2)
            #pragma unroll
            for (int r = 0; r < 4; ++r)
                cat[(mt*16 + l4*4 + r)*136 + (hg*2+hl)*HD_ + nt2*16 + l15] = f2bs(o_acc[hl][nt2][r]);
    __syncthreads();

    bool pred[4]; size_t tokb[4];
    #pragma unroll
    for (int r = 0; r < 4; ++r) {
        int m = mt*16 + l4*4 + r;
        int rr = m / WS_, cc = m % WS_;
        int hh = (wr*WS_ + rr + SS_) % Hp;
        int ww = (wc*WS_ + cc + SS_) % Wp;
        pred[r] = (m < NTOK_) && (hh < H1_) && (ww < W1_);
        tokb[r] = ((size_t)(b*H1_*W1_ + hh*W1_ + ww))*C_;
    }

    sh8 pa[4];
    #pragma unroll
    for (int kk = 0; kk < 4; ++kk)
        pa[kk] = *(const sh8*)(cat + (mt*16 + l15)*136 + kk*32 + l4*8);

    sh8 bpw[4], bpwn[4];
    #pragma unroll
    for (int kk = 0; kk < 4; ++kk)
        bpw[kk] = *(const sh8*)(wp + (hg*64 + l15)*C_ + kk*32 + l4*8);
    for (int nt = 0; nt < 4; ++nt) {
        int ch = hg*64 + nt*16 + l15;
        if (nt < 3) {
            #pragma unroll
            for (int kk = 0; kk < 4; ++kk)
                bpwn[kk] = *(const sh8*)(wp + (ch+16)*C_ + kk*32 + l4*8);
        }
        f32x4 acc = {0.f,0.f,0.f,0.f};
        #pragma unroll
        for (int kk = 0; kk < 4; ++kk)
            acc = __builtin_amdgcn_mfma_f32_16x16x32_bf16(pa[kk], bpw[kk], acc, 0,0,0);
        float pbv = projb[ch];
        #pragma unroll
        for (int r = 0; r < 4; ++r)
            if (pred[r])
                out[tokb[r] + ch] = x[tokb[r] + ch] + acc[r] + pbv;
        #pragma unroll
        for (int kk = 0; kk < 4; ++kk) bpw[kk] = bpwn[kk];
    }
}

// ---- mlp: 32 tokens/block, LDS 34304 B -> 4 blocks/CU, chunked fc1/fc2 ----
// LDS: xin bf16[32][136] (8704) | h2 bf16[32][136] (8704) | hv bf16[32][264] (16896)
__global__ __launch_bounds__(256, 4) void mlp_k(
    float* __restrict__ xio,
    const float* __restrict__ n2g, const float* __restrict__ n2b,
    const float* __restrict__ f1b, const float* __restrict__ f2b,
    const short* __restrict__ w1, const short* __restrict__ w2)
{
    __shared__ char smem[34304];
    short* xin = (short*)smem;
    short* h2  = (short*)(smem + 8704);
    short* hv  = (short*)(smem + 17408);

    const int tid = threadIdx.x;
    const int lane = tid & 63, wv = tid >> 6;
    const int l15 = lane & 15, l4 = lane >> 4;
    const int mt = wv & 1, nh = wv >> 1;
    const size_t base = (size_t)blockIdx.x * 32 * C_;

    // stage 32 tokens, convert to bf16 (residual precision loss ~0.006 << thr)
    for (int i = tid; i < 1024; i += 256) {
        float4 v = ((const float4*)(xio + base))[i];
        int row = i >> 5, c4 = (i & 31) * 4;
        xin[row*136 + c4 + 0] = f2bs(v.x);
        xin[row*136 + c4 + 1] = f2bs(v.y);
        xin[row*136 + c4 + 2] = f2bs(v.z);
        xin[row*136 + c4 + 3] = f2bs(v.w);
    }
    __syncthreads();

    // LN2: 8 threads per token
    {
        int tok = tid >> 3, sub = tid & 7;
        float s = 0.f, sq = 0.f;
        float vbuf[16];
        #pragma unroll
        for (int c = 0; c < 16; ++c) {
            float v = bs2f(xin[tok*136 + sub*16 + c]);
            vbuf[c] = v; s += v; sq += v*v;
        }
        #pragma unroll
        for (int off = 1; off < 8; off <<= 1) {
            s  += __shfl_xor(s, off);
            sq += __shfl_xor(sq, off);
        }
        float mean = s * (1.f/128.f);
        float var  = sq * (1.f/128.f) - mean*mean;
        float rstd = rsqrtf(var + 1e-5f);
        #pragma unroll
        for (int c = 0; c < 16; ++c) {
            int ch = sub*16 + c;
            h2[tok*136 + ch] = f2bs((vbuf[c] - mean)*rstd*n2g[ch] + n2b[ch]);
        }
    }
    __syncthreads();

    sh8 a1[4];
    #pragma unroll
    for (int kk = 0; kk < 4; ++kk)
        a1[kk] = *(const sh8*)(h2 + (mt*16 + l15)*136 + kk*32 + l4*8);

    f32x4 facc[4] = {};
    #pragma unroll 1
    for (int chunk = 0; chunk < 2; ++chunk) {
        const int c0 = chunk*256;
        // fc1 + GELU for hidden cols c0 + nh*128 .. +127 (8 n-tiles/wave)
        {
            sh8 b1[4], b1n[4];
            #pragma unroll
            for (int kk = 0; kk < 4; ++kk)
                b1[kk] = *(const sh8*)(w1 + (c0 + nh*128 + l15)*C_ + kk*32 + l4*8);
            for (int t = 0; t < 8; ++t) {
                int n = c0 + nh*128 + t*16 + l15;
                if (t < 7) {
                    #pragma unroll
                    for (int kk = 0; kk < 4; ++kk)
                        b1n[kk] = *(const sh8*)(w1 + (n+16)*C_ + kk*32 + l4*8);
                }
                f32x4 acc = {0.f,0.f,0.f,0.f};
                #pragma unroll
                for (int kk = 0; kk < 4; ++kk)
                    acc = __builtin_amdgcn_mfma_f32_16x16x32_bf16(a1[kk], b1[kk], acc, 0,0,0);
                float bias = f1b[n];
                #pragma unroll
                for (int r = 0; r < 4; ++r) {
                    float xv = acc[r] + bias;
                    float g = xv * 0.5f * (1.f + erff(xv * 0.70710678118654752f));
                    hv[(mt*16 + l4*4 + r)*264 + nh*128 + t*16 + l15] = f2bs(g);
                }
                #pragma unroll
                for (int kk = 0; kk < 4; ++kk) b1[kk] = b1n[kk];
            }
        }
        __syncthreads();
        // fc2 partial: K = c0..c0+255 (8 k-steps), out cols nh*64..+63 (4 n-tiles)
        {
            sh8 av = *(const sh8*)(hv + (mt*16 + l15)*264 + l4*8);
            sh8 avn;
            sh8 b2[4], b2n[4];
            #pragma unroll
            for (int nt = 0; nt < 4; ++nt)
                b2[nt] = *(const sh8*)(w2 + (nh*64 + nt*16 + l15)*512 + c0 + l4*8);
            for (int ks = 0; ks < 8; ++ks) {
                if (ks < 7) {
                    avn = *(const sh8*)(hv + (mt*16 + l15)*264 + (ks+1)*32 + l4*8);
                    #pragma unroll
                    for (int nt = 0; nt < 4; ++nt)
                        b2n[nt] = *(const sh8*)(w2 + (nh*64 + nt*16 + l15)*512 + c0 + (ks+1)*32 + l4*8);
                }
                #pragma unroll
                for (int nt = 0; nt < 4; ++nt)
                    facc[nt] = __builtin_amdgcn_mfma_f32_16x16x32_bf16(av, b2[nt], facc[nt], 0,0,0);
                av = avn;
                #pragma unroll
                for (int nt = 0; nt < 4; ++nt) b2[nt] = b2n[nt];
            }
        }
        if (chunk == 0) __syncthreads();   // hv rewritten by next fc1
    }

    // epilogue: +bias +residual, write back in place
    #pragma unroll
    for (int nt = 0; nt < 4; ++nt) {
        int ch = nh*64 + nt*16 + l15;
        float bias = f2b[ch];
        #pragma unroll
        for (int r = 0; r < 4; ++r) {
            int m = mt*16 + l4*4 + r;
            xio[base + m*C_ + ch] = bs2f(xin[m*136 + ch]) + facc[nt][r] + bias;
        }
    }
}

extern "C" void kernel_launch(void* const* d_in, const int* in_sizes, int n_in,
                              void* d_out, int out_size, void* d_ws, size_t ws_size,
                              hipStream_t stream) {
    const float* x    = (const float*)d_in[0];
    const float* n1g  = (const float*)d_in[1];
    const float* n1b  = (const float*)d_in[2];
    const float* qkvw = (const float*)d_in[3];
    const float* qkvb = (const float*)d_in[4];
    const float* rpb  = (const float*)d_in[5];
    const float* pw   = (const float*)d_in[6];
    const float* pb   = (const float*)d_in[7];
    const float* n2g  = (const float*)d_in[8];
    const float* n2b  = (const float*)d_in[9];
    const float* f1w  = (const float*)d_in[10];
    const float* f1b  = (const float*)d_in[11];
    const float* f2w  = (const float*)d_in[12];
    const float* f2b  = (const float*)d_in[13];

    short* ws = (short*)d_ws;          // bf16 transposed weights
    const short* wq = ws;
    const short* wp = ws + 49152;
    const short* w1 = ws + 65536;
    const short* w2 = ws + 131072;
    float* xio = (float*)d_out;

    hipLaunchKernelGGL(prep_k, dim3(768), dim3(256), 0, stream, qkvw, pw, f1w, f2w, ws);
    hipLaunchKernelGGL(win_attn, dim3(B_*NWIN_), dim3(512), 0, stream,
                       x, n1g, n1b, qkvb, rpb, pb, wq, wp, xio);
    hipLaunchKernelGGL(mlp_k, dim3(B_*H1_*W1_/32), dim3(256), 0, stream,
                       xio, n2g, n2b, f1b, f2b, w1, w2);
}

// Round 10
// 413.253 us; speedup vs baseline: 1.6076x; 1.0871x over previous
//
#include <hip/hip_runtime.h>
#include <hip/hip_bf16.h>

#define B_ 64
#define H1_ 64
#define W1_ 32
#define Hp 70
#define Wp 35
#define C_ 128
#define NH_ 4
#define HD_ 32
#define WS_ 7
#define SS_ 3
#define NWC_ 5
#define NWIN_ 50
#define NTOK_ 49
#define SCALE_ 0.17677669529663687f

typedef __hip_bfloat16 bf16;
typedef __attribute__((ext_vector_type(8))) short sh8;     // 8 bf16 = 4 VGPR
typedef __attribute__((ext_vector_type(4))) float f32x4;   // MFMA acc

__device__ __forceinline__ float bs2f(short s) {
    unsigned int u = ((unsigned int)(unsigned short)s) << 16;
    float f; __builtin_memcpy(&f, &u, 4); return f;
}
__device__ __forceinline__ short f2bs(float f) {
    bf16 h = __float2bfloat16(f);
    return *reinterpret_cast<short*>(&h);
}

// ---- prep: fp32 weights -> bf16, transposed to [N][K] for MFMA B-fragments ----
__global__ void prep_k(const float* __restrict__ qkvw, const float* __restrict__ projw,
                       const float* __restrict__ f1w, const float* __restrict__ f2w,
                       short* __restrict__ ws) {
    int tid = blockIdx.x * 256 + threadIdx.x;          // 768*256 = 196608 total
    if (tid < 49152) {
        int n = tid >> 7, k = tid & 127;               // qkv_w [128][384]
        ws[tid] = f2bs(qkvw[k*384 + n]);
    } else if (tid < 65536) {
        int t = tid - 49152; int n = t >> 7, k = t & 127;   // proj_w [128][128]
        ws[tid] = f2bs(projw[k*128 + n]);
    } else if (tid < 131072) {
        int t = tid - 65536; int n = t >> 7, k = t & 127;   // fc1_w [128][512]
        ws[tid] = f2bs(f1w[k*512 + n]);
    } else if (tid < 196608) {
        int t = tid - 131072; int n = t >> 9, k = t & 511;  // fc2_w [512][128]
        ws[tid] = f2bs(f2w[k*128 + n]);
    }
}

// ---- win_attn, 8 waves (unchanged from r9) ----
__global__ __launch_bounds__(512, 4) void win_attn(
    const float* __restrict__ x,
    const float* __restrict__ n1g, const float* __restrict__ n1b,
    const float* __restrict__ qkvb, const float* __restrict__ rpb,
    const float* __restrict__ projb,
    const short* __restrict__ wq, const short* __restrict__ wp,
    float* __restrict__ out)
{
    __shared__ char smem[71680];
    short* q_s = (short*)smem;
    short* k_s = (short*)(smem + 17408);
    short* cat = (short*)(smem + 17408);
    short* vt  = (short*)(smem + 34816);
    short* xsp = (short*)(smem + 53248);
    short* p_s = (short*)(smem + 53248);

    const int tid = threadIdx.x;
    const int lane = tid & 63, wv = tid >> 6;
    const int l15 = lane & 15, l4 = lane >> 4;
    const int mt = wv & 3, hg = wv >> 2;
    const int bw = blockIdx.x;
    const int b = bw / NWIN_, win = bw % NWIN_;
    const int wr = win / NWC_, wc = win % NWC_;

    // ================= phase A: qkv (2 passes of 32 rows) =================
    #pragma unroll
    for (int pass = 0; pass < 2; ++pass) {
        const int t0 = pass * 32;
        for (int n = wv; n < 32; n += 8) {
            int gtok = t0 + n;
            int r = gtok / WS_, cc = gtok % WS_;
            int h = (wr*WS_ + r + SS_) % Hp;
            int w = (wc*WS_ + cc + SS_) % Wp;
            int c0 = lane*2;
            float v0 = 0.f, v1 = 0.f;
            if (gtok < NTOK_ && h < H1_ && w < W1_) {
                const float* src = x + ((size_t)(b*H1_*W1_ + h*W1_ + w))*C_ + c0;
                v0 = src[0]; v1 = src[1];
            }
            float s = v0 + v1, sq = v0*v0 + v1*v1;
            #pragma unroll
            for (int off = 32; off; off >>= 1) {
                s  += __shfl_xor(s, off);
                sq += __shfl_xor(sq, off);
            }
            float mean = s * (1.f/128.f);
            float var  = sq * (1.f/128.f) - mean*mean;
            float rstd = rsqrtf(var + 1e-5f);
            xsp[n*136 + c0]   = f2bs((v0-mean)*rstd*n1g[c0]   + n1b[c0]);
            xsp[n*136 + c0+1] = f2bs((v1-mean)*rstd*n1g[c0+1] + n1b[c0+1]);
        }
        __syncthreads();

        sh8 a[2][4];
        #pragma unroll
        for (int m = 0; m < 2; ++m)
            #pragma unroll
            for (int kk = 0; kk < 4; ++kk)
                a[m][kk] = *(const sh8*)(xsp + (m*16 + l15)*136 + kk*32 + l4*8);

        sh8 bq[4], bqn[4];
        {
            int n0 = (wv*3)*16 + l15;
            #pragma unroll
            for (int kk = 0; kk < 4; ++kk)
                bq[kk] = *(const sh8*)(wq + n0*C_ + kk*32 + l4*8);
        }
        for (int t = 0; t < 3; ++t) {
            int n0 = (wv*3 + t)*16 + l15;
            if (t < 2) {
                int n1 = n0 + 16;
                #pragma unroll
                for (int kk = 0; kk < 4; ++kk)
                    bqn[kk] = *(const sh8*)(wq + n1*C_ + kk*32 + l4*8);
            }
            f32x4 acc0 = {0.f,0.f,0.f,0.f}, acc1 = {0.f,0.f,0.f,0.f};
            #pragma unroll
            for (int kk = 0; kk < 4; ++kk) {
                acc0 = __builtin_amdgcn_mfma_f32_16x16x32_bf16(a[0][kk], bq[kk], acc0, 0,0,0);
                acc1 = __builtin_amdgcn_mfma_f32_16x16x32_bf16(a[1][kk], bq[kk], acc1, 0,0,0);
            }
            int mat = n0 >> 7, c = n0 & 127;
            float bias = qkvb[n0];
            float scl = (mat == 0) ? SCALE_ : 1.f;
            #pragma unroll
            for (int r = 0; r < 4; ++r) {
                int m0 = t0 + l4*4 + r;
                int m1 = m0 + 16;
                float v0c = (acc0[r] + bias) * scl;
                float v1c = (acc1[r] + bias) * scl;
                if (mat == 0)      { q_s[m0*136 + c] = f2bs(v0c); q_s[m1*136 + c] = f2bs(v1c); }
                else if (mat == 1) { k_s[m0*136 + c] = f2bs(v0c); k_s[m1*136 + c] = f2bs(v1c); }
                else               { vt[c*72 + m0]   = f2bs(v0c); vt[c*72 + m1]   = f2bs(v1c); }
            }
            #pragma unroll
            for (int kk = 0; kk < 4; ++kk) bq[kk] = bqn[kk];
        }
        __syncthreads();
    }

    // ================= phase B: attention; wave = (mt, heads hg*2..hg*2+1) =================
    int zi_r[4], ri_r[4], ci_r[4]; bool iv[4];
    #pragma unroll
    for (int r = 0; r < 4; ++r) {
        int i = mt*16 + l4*4 + r;
        iv[r] = (i < NTOK_);
        int ri = i / WS_, ci = i % WS_;
        ri_r[r] = ri; ci_r[r] = ci;
        int hi = wr*WS_ + ri, wi = wc*WS_ + ci;
        zi_r[r] = (hi < 63 ? 0 : (hi < 67 ? 1 : 2))*3 + (wi < 28 ? 0 : (wi < 32 ? 1 : 2));
    }
    int zj_n[4], rj_n[4], cj_n[4]; bool jv[4];
    #pragma unroll
    for (int nt = 0; nt < 4; ++nt) {
        int j = nt*16 + l15;
        jv[nt] = (j < NTOK_);
        int rj = j / WS_, cj = j % WS_;
        rj_n[nt] = rj; cj_n[nt] = cj;
        int hj = wr*WS_ + rj, wj = wc*WS_ + cj;
        zj_n[nt] = (hj < 63 ? 0 : (hj < 67 ? 1 : 2))*3 + (wj < 28 ? 0 : (wj < 32 ? 1 : 2));
    }

    short* myp = p_s + wv*16*72;     // per-wave P slice
    f32x4 o_acc[2][2] = {};
    #pragma unroll
    for (int hl = 0; hl < 2; ++hl) {
        const int h = hg*2 + hl;
        sh8 aq = *(const sh8*)(q_s + (mt*16 + l15)*136 + h*HD_ + l4*8);
        f32x4 s[4];
        #pragma unroll
        for (int nt = 0; nt < 4; ++nt) {
            sh8 bk = *(const sh8*)(k_s + (nt*16 + l15)*136 + h*HD_ + l4*8);
            f32x4 z = {0.f,0.f,0.f,0.f};
            s[nt] = __builtin_amdgcn_mfma_f32_16x16x32_bf16(aq, bk, z, 0,0,0);
        }
        #pragma unroll
        for (int nt = 0; nt < 4; ++nt)
            #pragma unroll
            for (int r = 0; r < 4; ++r) {
                float sv = s[nt][r];
                if (iv[r] && jv[nt]) {
                    sv += rpb[(size_t)((ri_r[r]-rj_n[nt]+6)*13 + (ci_r[r]-cj_n[nt]+6))*4 + h];
                    if (zi_r[r] != zj_n[nt]) sv -= 100.f;
                } else sv = -1e30f;
                s[nt][r] = sv;
            }
        #pragma unroll
        for (int r = 0; r < 4; ++r) {
            float m0 = fmaxf(fmaxf(s[0][r], s[1][r]), fmaxf(s[2][r], s[3][r]));
            #pragma unroll
            for (int off = 1; off < 16; off <<= 1) m0 = fmaxf(m0, __shfl_xor(m0, off));
            float ls = 0.f;
            #pragma unroll
            for (int nt = 0; nt < 4; ++nt) {
                float e = __expf(s[nt][r] - m0);
                s[nt][r] = e; ls += e;
            }
            #pragma unroll
            for (int off = 1; off < 16; off <<= 1) ls += __shfl_xor(ls, off);
            float inv = 1.f / ls;
            #pragma unroll
            for (int nt = 0; nt < 4; ++nt)
                myp[(l4*4 + r)*72 + nt*16 + l15] = f2bs(s[nt][r] * inv);
        }
        sh8 ap0 = *(const sh8*)(myp + l15*72 + l4*8);
        sh8 ap1 = *(const sh8*)(myp + l15*72 + 32 + l4*8);
        #pragma unroll
        for (int nt2 = 0; nt2 < 2; ++nt2) {
            sh8 bv0 = *(const sh8*)(vt + (h*HD_ + nt2*16 + l15)*72 + l4*8);
            sh8 bv1 = *(const sh8*)(vt + (h*HD_ + nt2*16 + l15)*72 + 32 + l4*8);
            o_acc[hl][nt2] = __builtin_amdgcn_mfma_f32_16x16x32_bf16(ap0, bv0, o_acc[hl][nt2], 0,0,0);
            o_acc[hl][nt2] = __builtin_amdgcn_mfma_f32_16x16x32_bf16(ap1, bv1, o_acc[hl][nt2], 0,0,0);
        }
    }

    __syncthreads();   // k_s reads done -> cat may overlay

    // ================= phase C: cat -> proj -> +residual scatter =================
    #pragma unroll
    for (int hl = 0; hl < 2; ++hl)
        #pragma unroll
        for (int nt2 = 0; nt2 < 2; ++nt2)
            #pragma unroll
            for (int r = 0; r < 4; ++r)
                cat[(mt*16 + l4*4 + r)*136 + (hg*2+hl)*HD_ + nt2*16 + l15] = f2bs(o_acc[hl][nt2][r]);
    __syncthreads();

    bool pred[4]; size_t tokb[4];
    #pragma unroll
    for (int r = 0; r < 4; ++r) {
        int m = mt*16 + l4*4 + r;
        int rr = m / WS_, cc = m % WS_;
        int hh = (wr*WS_ + rr + SS_) % Hp;
        int ww = (wc*WS_ + cc + SS_) % Wp;
        pred[r] = (m < NTOK_) && (hh < H1_) && (ww < W1_);
        tokb[r] = ((size_t)(b*H1_*W1_ + hh*W1_ + ww))*C_;
    }

    sh8 pa[4];
    #pragma unroll
    for (int kk = 0; kk < 4; ++kk)
        pa[kk] = *(const sh8*)(cat + (mt*16 + l15)*136 + kk*32 + l4*8);

    sh8 bpw[4], bpwn[4];
    #pragma unroll
    for (int kk = 0; kk < 4; ++kk)
        bpw[kk] = *(const sh8*)(wp + (hg*64 + l15)*C_ + kk*32 + l4*8);
    for (int nt = 0; nt < 4; ++nt) {
        int ch = hg*64 + nt*16 + l15;
        if (nt < 3) {
            #pragma unroll
            for (int kk = 0; kk < 4; ++kk)
                bpwn[kk] = *(const sh8*)(wp + (ch+16)*C_ + kk*32 + l4*8);
        }
        f32x4 acc = {0.f,0.f,0.f,0.f};
        #pragma unroll
        for (int kk = 0; kk < 4; ++kk)
            acc = __builtin_amdgcn_mfma_f32_16x16x32_bf16(pa[kk], bpw[kk], acc, 0,0,0);
        float pbv = projb[ch];
        #pragma unroll
        for (int r = 0; r < 4; ++r)
            if (pred[r])
                out[tokb[r] + ch] = x[tokb[r] + ch] + acc[r] + pbv;
        #pragma unroll
        for (int kk = 0; kk < 4; ++kk) bpw[kk] = bpwn[kk];
    }
}

// ---- mlp v2: 64 tokens/block, 512 threads, LDS 51200 B -> 3 blocks/CU ----
// wave = (mh = token-half, ng = col-group). Each weight fragment feeds 2 m-tiles.
// LDS: h2 bf16[64][136] (17408, staged + LN2'd in place) | hv bf16[64][264] (33792)
__global__ __launch_bounds__(512, 6) void mlp_k(
    float* __restrict__ xio,
    const float* __restrict__ n2g, const float* __restrict__ n2b,
    const float* __restrict__ f1b, const float* __restrict__ f2b,
    const short* __restrict__ w1, const short* __restrict__ w2)
{
    __shared__ char smem[51200];
    short* h2 = (short*)smem;
    short* hv = (short*)(smem + 17408);

    const int tid = threadIdx.x;
    const int lane = tid & 63, wv = tid >> 6;
    const int l15 = lane & 15, l4 = lane >> 4;
    const int mh = wv & 1, ng = wv >> 1;
    const size_t base = (size_t)blockIdx.x * 64 * C_;

    // stage 64 tokens as bf16
    for (int i = tid; i < 2048; i += 512) {
        float4 v = ((const float4*)(xio + base))[i];
        int row = i >> 5, c4 = (i & 31) * 4;
        h2[row*136 + c4 + 0] = f2bs(v.x);
        h2[row*136 + c4 + 1] = f2bs(v.y);
        h2[row*136 + c4 + 2] = f2bs(v.z);
        h2[row*136 + c4 + 3] = f2bs(v.w);
    }
    __syncthreads();

    // LN2 in place (8 threads/token; each thread owns the 16 channels it rewrites)
    {
        int tok = tid >> 3, sub = tid & 7;
        float vbuf[16];
        float s = 0.f, sq = 0.f;
        #pragma unroll
        for (int c = 0; c < 16; ++c) {
            float v = bs2f(h2[tok*136 + sub*16 + c]);
            vbuf[c] = v; s += v; sq += v*v;
        }
        #pragma unroll
        for (int off = 1; off < 8; off <<= 1) {
            s  += __shfl_xor(s, off);
            sq += __shfl_xor(sq, off);
        }
        float mean = s * (1.f/128.f);
        float var  = sq * (1.f/128.f) - mean*mean;
        float rstd = rsqrtf(var + 1e-5f);
        #pragma unroll
        for (int c = 0; c < 16; ++c) {
            int ch = sub*16 + c;
            h2[tok*136 + ch] = f2bs((vbuf[c] - mean)*rstd*n2g[ch] + n2b[ch]);
        }
    }
    __syncthreads();

    f32x4 facc[2][2] = {};
    #pragma unroll 1
    for (int chunk = 0; chunk < 2; ++chunk) {
        const int c0 = chunk*256;
        // ---- fc1 + GELU: chunk-local cols ng*64..+63, both m-tiles ----
        {
            sh8 b1[4], b1n[4];
            #pragma unroll
            for (int kk = 0; kk < 4; ++kk)
                b1[kk] = *(const sh8*)(w1 + (size_t)(c0 + ng*64 + l15)*C_ + kk*32 + l4*8);
            for (int t = 0; t < 4; ++t) {
                int n = c0 + ng*64 + t*16 + l15;
                if (t < 3) {
                    #pragma unroll
                    for (int kk = 0; kk < 4; ++kk)
                        b1n[kk] = *(const sh8*)(w1 + (size_t)(n + 16)*C_ + kk*32 + l4*8);
                }
                float bias = f1b[n];
                #pragma unroll
                for (int mt2 = 0; mt2 < 2; ++mt2) {
                    int mrow = (mh*2 + mt2)*16;
                    f32x4 acc = {0.f,0.f,0.f,0.f};
                    #pragma unroll
                    for (int kk = 0; kk < 4; ++kk) {
                        sh8 av = *(const sh8*)(h2 + (mrow + l15)*136 + kk*32 + l4*8);
                        acc = __builtin_amdgcn_mfma_f32_16x16x32_bf16(av, b1[kk], acc, 0,0,0);
                    }
                    #pragma unroll
                    for (int r = 0; r < 4; ++r) {
                        float xv = acc[r] + bias;
                        float g = xv * 0.5f * (1.f + erff(xv * 0.70710678118654752f));
                        hv[(mrow + l4*4 + r)*264 + ng*64 + t*16 + l15] = f2bs(g);
                    }
                }
                #pragma unroll
                for (int kk = 0; kk < 4; ++kk) b1[kk] = b1n[kk];
            }
        }
        __syncthreads();
        // ---- fc2 partial: K = [c0, c0+256), out cols ng*32..+31, both m-tiles ----
        {
            sh8 b2[2], b2n[2];
            #pragma unroll
            for (int nt = 0; nt < 2; ++nt)
                b2[nt] = *(const sh8*)(w2 + (size_t)(ng*32 + nt*16 + l15)*512 + c0 + l4*8);
            for (int ks = 0; ks < 8; ++ks) {
                if (ks < 7) {
                    #pragma unroll
                    for (int nt = 0; nt < 2; ++nt)
                        b2n[nt] = *(const sh8*)(w2 + (size_t)(ng*32 + nt*16 + l15)*512 + c0 + (ks+1)*32 + l4*8);
                }
                #pragma unroll
                for (int mt2 = 0; mt2 < 2; ++mt2) {
                    sh8 av = *(const sh8*)(hv + ((mh*2 + mt2)*16 + l15)*264 + ks*32 + l4*8);
                    facc[mt2][0] = __builtin_amdgcn_mfma_f32_16x16x32_bf16(av, b2[0], facc[mt2][0], 0,0,0);
                    facc[mt2][1] = __builtin_amdgcn_mfma_f32_16x16x32_bf16(av, b2[1], facc[mt2][1], 0,0,0);
                }
                b2[0] = b2n[0]; b2[1] = b2n[1];
            }
        }
        if (chunk == 0) __syncthreads();   // hv rewritten by next fc1
    }

    // epilogue: + bias + residual (re-read own elements from global, L2-hot)
    #pragma unroll
    for (int mt2 = 0; mt2 < 2; ++mt2)
        #pragma unroll
        for (int nt = 0; nt < 2; ++nt) {
            int oc = ng*32 + nt*16 + l15;
            float bias = f2b[oc];
            #pragma unroll
            for (int r = 0; r < 4; ++r) {
                int m = (mh*2 + mt2)*16 + l4*4 + r;
                size_t idx = base + (size_t)m*C_ + oc;
                xio[idx] = xio[idx] + facc[mt2][nt][r] + bias;
            }
        }
}

extern "C" void kernel_launch(void* const* d_in, const int* in_sizes, int n_in,
                              void* d_out, int out_size, void* d_ws, size_t ws_size,
                              hipStream_t stream) {
    const float* x    = (const float*)d_in[0];
    const float* n1g  = (const float*)d_in[1];
    const float* n1b  = (const float*)d_in[2];
    const float* qkvw = (const float*)d_in[3];
    const float* qkvb = (const float*)d_in[4];
    const float* rpb  = (const float*)d_in[5];
    const float* pw   = (const float*)d_in[6];
    const float* pb   = (const float*)d_in[7];
    const float* n2g  = (const float*)d_in[8];
    const float* n2b  = (const float*)d_in[9];
    const float* f1w  = (const float*)d_in[10];
    const float* f1b  = (const float*)d_in[11];
    const float* f2w  = (const float*)d_in[12];
    const float* f2b  = (const float*)d_in[13];

    short* ws = (short*)d_ws;          // bf16 transposed weights
    const short* wq = ws;
    const short* wp = ws + 49152;
    const short* w1 = ws + 65536;
    const short* w2 = ws + 131072;
    float* xio = (float*)d_out;

    hipLaunchKernelGGL(prep_k, dim3(768), dim3(256), 0, stream, qkvw, pw, f1w, f2w, ws);
    hipLaunchKernelGGL(win_attn, dim3(B_*NWIN_), dim3(512), 0, stream,
                       x, n1g, n1b, qkvb, rpb, pb, wq, wp, xio);
    hipLaunchKernelGGL(mlp_k, dim3(B_*H1_*W1_/64), dim3(512), 0, stream,
                       xio, n2g, n2b, f1b, f2b, w1, w2);
}